// Round 1
// baseline (1263.718 us; speedup 1.0000x reference)
//
#include <hip/hip_runtime.h>
#include <cmath>

// Problem constants
#define BB 128
#define MM 64
#define DD 64
#define PP 1024
#define AN 21
#define NPAIR 2016            // M*(M-1)/2
#define PT 16                 // pairs per wave-tile
#define TILES_PER_B (NPAIR / PT)        // 126
#define TOTAL_TILES (BB * TILES_PER_B)  // 16128

__device__ __forceinline__ float gelu_exact(float x) {
    // exact GELU (matches approximate=False): 0.5*x*(1+erf(x/sqrt(2)))
    return 0.5f * x * (1.0f + erff(x * 0.70710678118654752f));
}

// ---------------------------------------------------------------------------
// Kernel 1: e = pos_table[pos] + aa_table[aa];  u = e @ W1[:64], v = e @ W1[64:]
// Also zeroes the output diagonal (never written by the pair kernel).
// One wave per (b, m). Grid = B*M/4 blocks of 256 threads (4 waves).
// ---------------------------------------------------------------------------
__global__ __launch_bounds__(256) void k_embed_uv(
    const int* __restrict__ positions, const int* __restrict__ amino,
    const float* __restrict__ pos_table, const float* __restrict__ aa_table,
    const float* __restrict__ W1,
    float* __restrict__ u, float* __restrict__ v, float* __restrict__ out)
{
    __shared__ __align__(16) float es[4][DD];
    const int wave = threadIdx.x >> 6;
    const int lane = threadIdx.x & 63;
    const int idx = blockIdx.x * 4 + wave;   // b*M + m  (grid sized exactly)

    int p = positions[idx];
    p = p < 0 ? 0 : (p > PP - 1 ? PP - 1 : p);
    int a = amino[idx];
    a = a < 0 ? 0 : (a > AN - 1 ? AN - 1 : a);

    const float e = pos_table[p * DD + lane] + aa_table[a * DD + lane];
    es[wave][lane] = e;
    // wave-synchronous LDS: ensure write visible before cross-lane reads
    asm volatile("s_waitcnt lgkmcnt(0)" ::: "memory");

    float uacc = 0.0f, vacc = 0.0f;
#pragma unroll
    for (int k = 0; k < DD; ++k) {
        const float ek = es[wave][k];              // broadcast read
        uacc = fmaf(ek, W1[k * DD + lane], uacc);        // W1 rows 0..63
        vacc = fmaf(ek, W1[(DD + k) * DD + lane], vacc); // W1 rows 64..127
    }
    u[idx * DD + lane] = uacc;
    v[idx * DD + lane] = vacc;

    if (lane == 0) {
        const int b = idx >> 6, m = idx & 63;
        out[b * MM * MM + m * MM + m] = 0.0f;      // diagonal
    }
}

// ---------------------------------------------------------------------------
// Kernel 2: for each pair (i<j): h1 = gelu(u_i + v_j + b1);
//           h2 = gelu(h1 @ W2 + b2); s = h2 . W3 + b3;
//           out[b,i,j] = out[b,j,i] = s.
// One wave per 16-pair tile; lane = output feature. W2 column in VGPRs,
// h1 staged in per-wave LDS and broadcast-read as float4.
// ---------------------------------------------------------------------------
__global__ __launch_bounds__(256) void k_pair_mlp(
    const float* __restrict__ u, const float* __restrict__ v,
    const float* __restrict__ W2, const float* __restrict__ b1,
    const float* __restrict__ b2, const float* __restrict__ W3,
    const float* __restrict__ b3, float* __restrict__ out)
{
    __shared__ __align__(16) float h1s[4][PT][DD];
    const int wave = threadIdx.x >> 6;
    const int lane = threadIdx.x & 63;

    // Per-lane constants: column lane of W2, biases, W3
    float w2c[DD];
#pragma unroll
    for (int k = 0; k < DD; ++k) w2c[k] = W2[k * DD + lane];
    const float b1l = b1[lane];
    const float b2l = b2[lane];
    const float w3l = W3[lane];
    const float b3s = b3[0];

    const int gwave = blockIdx.x * 4 + wave;
    const int nw = gridDim.x * 4;

    for (int tile = gwave; tile < TOTAL_TILES; tile += nw) {
        const int b = tile / TILES_PER_B;
        const int t0 = (tile - b * TILES_PER_B) * PT;

        // decode first pair index: j such that j(j-1)/2 <= t0 < j(j+1)/2
        int j0 = (int)((1.0f + sqrtf(1.0f + 8.0f * (float)t0)) * 0.5f);
        if (j0 * (j0 - 1) / 2 > t0) --j0;
        if (j0 * (j0 + 1) / 2 <= t0) ++j0;
        int i0 = t0 - j0 * (j0 - 1) / 2;

        const float* __restrict__ ub = u + b * (MM * DD);
        const float* __restrict__ vb = v + b * (MM * DD);

        // ----- layer 1: h1 for PT pairs into LDS -----
        {
            int i = i0, j = j0;
#pragma unroll
            for (int pp = 0; pp < PT; ++pp) {
                const float x = ub[i * DD + lane] + vb[j * DD + lane] + b1l;
                h1s[wave][pp][lane] = gelu_exact(x);
                if (++i == j) { i = 0; ++j; }
            }
        }
        asm volatile("s_waitcnt lgkmcnt(0)" ::: "memory");

        // ----- layer 2: acc[pp] = b2 + h1[pp] @ W2[:,lane] -----
        float acc[PT];
#pragma unroll
        for (int pp = 0; pp < PT; ++pp) acc[pp] = b2l;
#pragma unroll
        for (int k = 0; k < DD; k += 4) {
#pragma unroll
            for (int pp = 0; pp < PT; ++pp) {
                const float4 h4 = *reinterpret_cast<const float4*>(&h1s[wave][pp][k]);
                acc[pp] = fmaf(h4.x, w2c[k + 0], acc[pp]);
                acc[pp] = fmaf(h4.y, w2c[k + 1], acc[pp]);
                acc[pp] = fmaf(h4.z, w2c[k + 2], acc[pp]);
                acc[pp] = fmaf(h4.w, w2c[k + 3], acc[pp]);
            }
        }

        // ----- layer 3: gelu, dot with W3, wave-reduce, mirrored write -----
        float* __restrict__ ob = out + b * (MM * MM);
        {
            int i = i0, j = j0;
#pragma unroll
            for (int pp = 0; pp < PT; ++pp) {
                float g = gelu_exact(acc[pp]) * w3l;
#pragma unroll
                for (int off = 32; off >= 1; off >>= 1)
                    g += __shfl_xor(g, off, 64);
                if (lane == 0) {
                    const float s = g + b3s;
                    ob[i * MM + j] = s;
                    ob[j * MM + i] = s;
                }
                if (++i == j) { i = 0; ++j; }
            }
        }
    }
}

extern "C" void kernel_launch(void* const* d_in, const int* in_sizes, int n_in,
                              void* d_out, int out_size, void* d_ws, size_t ws_size,
                              hipStream_t stream) {
    const int*   positions = (const int*)  d_in[0];
    const int*   amino     = (const int*)  d_in[1];
    const float* pos_table = (const float*)d_in[2];
    const float* aa_table  = (const float*)d_in[3];
    const float* W1        = (const float*)d_in[4];
    const float* b1        = (const float*)d_in[5];
    const float* W2        = (const float*)d_in[6];
    const float* b2        = (const float*)d_in[7];
    const float* W3        = (const float*)d_in[8];
    const float* b3        = (const float*)d_in[9];
    float* out = (float*)d_out;

    float* u = (float*)d_ws;                  // [B*M, 64]  (2 MB)
    float* v = u + (size_t)BB * MM * DD;      // [B*M, 64]  (2 MB)

    // Kernel 1: B*M = 8192 waves -> 2048 blocks of 4 waves
    k_embed_uv<<<2048, 256, 0, stream>>>(positions, amino, pos_table, aa_table,
                                         W1, u, v, out);
    // Kernel 2: 16128 tiles, grid-stride over 1008 blocks (4032 waves, ~4 tiles each)
    k_pair_mlp<<<1008, 256, 0, stream>>>(u, v, W2, b1, b2, W3, b3, out);
}